// Round 13
// baseline (190.384 us; speedup 1.0000x reference)
//
#include <hip/hip_runtime.h>
#include <math.h>

#define T_TOK 4096
#define C_DIM 256
#define EPSF  1e-5f
// hd^-0.5 * log2(e): folded into q-projection weights/bias -> scores in log2 domain
#define SC_QL (0.17677669529663687f * 1.4426950408889634f)

typedef short  bf16x8  __attribute__((ext_vector_type(8)));
typedef float  f32x4   __attribute__((ext_vector_type(4)));
typedef ushort ushort8 __attribute__((ext_vector_type(8)));
typedef unsigned uint4v __attribute__((ext_vector_type(4)));
typedef unsigned uint2v __attribute__((ext_vector_type(2)));

__device__ __forceinline__ short f2bf(float f) {
    unsigned u = __builtin_bit_cast(unsigned, f);
    unsigned r = (u + 0x7FFFu + ((u >> 16) & 1u)) >> 16;
    return (short)r;
}
__device__ __forceinline__ float bf2f(ushort u) {
    return __builtin_bit_cast(float, ((unsigned)u) << 16);
}
// pack two f32 -> bf16 pair (a=low, b=high), round-half-up via v_perm
__device__ __forceinline__ unsigned pk_bf16(float a, float b) {
    const unsigned ua = __builtin_bit_cast(unsigned, a) + 0x8000u;
    const unsigned ub = __builtin_bit_cast(unsigned, b) + 0x8000u;
    return __builtin_amdgcn_perm(ub, ua, 0x07060302u);
}
// single-instruction pack (RNE) for the attention P-matrix
__device__ __forceinline__ unsigned cvtpk_bf16(float a, float b) {
    unsigned r;
    asm("v_cvt_pk_bf16_f32 %0, %1, %2" : "=v"(r) : "v"(a), "v"(b));
    return r;
}
// gfx950 dual-dest lane-group swaps (exchange across lane bit 5 / bit 4)
__device__ __forceinline__ void plswap32(unsigned &a, unsigned &b) {
    asm("v_permlane32_swap_b32 %0, %1" : "+v"(a), "+v"(b));
}
__device__ __forceinline__ void plswap16(unsigned &a, unsigned &b) {
    asm("v_permlane16_swap_b32 %0, %1" : "+v"(a), "+v"(b));
}
template <int CTRL>
__device__ __forceinline__ float dppf(float x) {
    return __builtin_bit_cast(float,
        __builtin_amdgcn_mov_dpp(__builtin_bit_cast(int, x), CTRL, 0xF, 0xF, true));
}
__device__ __forceinline__ float rowsum16(float x) {
    x += dppf<0xB1>(x);
    x += dppf<0x4E>(x);
    x += dppf<0x141>(x);
    x += dppf<0x140>(x);
    return x;
}
// gelu, tanh form via exp2+rcp: v*t/(t+1), t=exp2(v*(2.302208+0.1029431 v^2))
__device__ __forceinline__ float gelu_f(float v) {
    const float u  = v * v;
    const float w2 = fmaf(u, 0.10294310f, 2.30220800f);
    const float t  = __builtin_amdgcn_exp2f(v * w2);
    return v * t * __builtin_amdgcn_rcpf(t + 1.0f);
}
#define MFMA16(a, b, c) __builtin_amdgcn_mfma_f32_16x16x32_bf16(a, b, c, 0, 0, 0)

// ---------------------------------------------------------------------------
// prep: weights f32->bf16 arena only (q-rows of w_qkv/b_qkv scaled). grid 896.
// ---------------------------------------------------------------------------
__global__ __launch_bounds__(256) void prep_kernel(
    const float* __restrict__ w_in, const float* __restrict__ w_qkv,
    const float* __restrict__ w_ap, const float* __restrict__ w_ff1,
    const float* __restrict__ w_ff2, const float* __restrict__ w_out,
    const float* __restrict__ b_qkv, ushort* __restrict__ wbuf,
    float* __restrict__ bqs)
{
    const int gid = blockIdx.x * 256 + threadIdx.x;
    const int e0 = gid * 4;
    const float* src; int off; float sc = 1.f;
    if (e0 < 65536)       { src = w_in;  off = e0; }
    else if (e0 < 262144) { src = w_qkv; off = e0 - 65536; if (off < 65536) sc = SC_QL; }
    else if (e0 < 327680) { src = w_ap;  off = e0 - 262144; }
    else if (e0 < 589824) { src = w_ff1; off = e0 - 327680; }
    else if (e0 < 851968) { src = w_ff2; off = e0 - 589824; }
    else                  { src = w_out; off = e0 - 851968; }
    const float4 v = *(const float4*)(src + off);
    ushort4 o;
    o.x = (ushort)f2bf(v.x * sc); o.y = (ushort)f2bf(v.y * sc);
    o.z = (ushort)f2bf(v.z * sc); o.w = (ushort)f2bf(v.w * sc);
    *(ushort4*)(wbuf + e0) = o;
    if (gid < 192) {
        const float s2 = (gid < 64) ? SC_QL : 1.f;
        float4 b = ((const float4*)b_qkv)[gid];
        b.x *= s2; b.y *= s2; b.z *= s2; b.w *= s2;
        ((float4*)bqs)[gid] = b;
    }
}

// ---------------------------------------------------------------------------
// Fused pre-attention: BN + proj_in + LN1 + QKV. grid 256, block 1024
// (16 waves), 16 tokens per block. launch_bounds (1024,4): VGPR cap 128,
// weights preloaded 8-deep.
// ---------------------------------------------------------------------------
__global__ __launch_bounds__(1024, 4) void fused_pre(
    const float* __restrict__ x, const float* __restrict__ bn_g,
    const float* __restrict__ bn_b, const float* __restrict__ bn_m,
    const float* __restrict__ bn_v,
    const ushort* __restrict__ wb_in, const float* __restrict__ b_in,
    const float* __restrict__ ln1_g, const float* __restrict__ ln1_b,
    const ushort* __restrict__ wb_qkv, const float* __restrict__ bqs,
    float* __restrict__ ysum, ushort* __restrict__ qkvb)
{
    __shared__ ushort Atile[16 * 264];
    __shared__ ushort Ytile[16 * 264];
    __shared__ float  red[16][16][2];
    const int t0 = blockIdx.x * 16;
    const int tid = threadIdx.x, wv = tid >> 6, lane = tid & 63;
    const int c = lane & 15, g = lane >> 4;
    const int colp = wv * 16 + c;

    // early: preload proj_in weight frags (global, no dependencies)
    bf16x8 win[8];
    {
        const ushort* wp = wb_in + (size_t)colp * 256 + g * 8;
#pragma unroll
        for (int kc = 0; kc < 8; ++kc) win[kc] = *(const bf16x8*)(wp + kc * 32);
    }

    {   // BN + transpose: thread (cc, tt-group) reads 4 t of channel cc
        const int cc = tid >> 2;            // 0..255
        const int tt = (tid & 3) * 4;       // 0,4,8,12
        const float a = rsqrtf(bn_v[cc] + EPSF) * bn_g[cc];
        const float d = bn_b[cc] - bn_m[cc] * a;
        const float4 v = *(const float4*)(x + (size_t)cc * T_TOK + t0 + tt);
        Atile[(tt + 0) * 264 + cc] = (ushort)f2bf(fmaf(v.x, a, d));
        Atile[(tt + 1) * 264 + cc] = (ushort)f2bf(fmaf(v.y, a, d));
        Atile[(tt + 2) * 264 + cc] = (ushort)f2bf(fmaf(v.z, a, d));
        Atile[(tt + 3) * 264 + cc] = (ushort)f2bf(fmaf(v.w, a, d));
    }
    __syncthreads();

    // ---- proj_in: wave w -> cols [16w, 16w+16), one frag ----
    f32x4 accp = {};
#pragma unroll
    for (int kc = 0; kc < 8; ++kc) {
        const bf16x8 af = *(const bf16x8*)&Atile[c * 264 + kc * 32 + g * 8];
        accp = MFMA16(af, win[kc], accp);
    }
    {
        const float bb = b_in[colp];
        float vs[4], s1[4], s2[4];
#pragma unroll
        for (int rr = 0; rr < 4; ++rr) {
            const float v = accp[rr] + bb;
            vs[rr] = v; s1[rr] = v; s2[rr] = v * v;
        }
#pragma unroll
        for (int rr = 0; rr < 4; ++rr) { s1[rr] = rowsum16(s1[rr]); s2[rr] = rowsum16(s2[rr]); }
        if (c == 0) {
#pragma unroll
            for (int rr = 0; rr < 4; ++rr) {
                red[wv][4 * g + rr][0] = s1[rr];
                red[wv][4 * g + rr][1] = s2[rr];
            }
        }
        __syncthreads();
        if (tid < 32) {   // stage-2 reduce across 16 waves
            const int row = tid >> 1, j = tid & 1;
            float s = 0.f;
#pragma unroll
            for (int w = 0; w < 16; ++w) s += red[w][row][j];
            red[0][row][j] = s;
        }
        __syncthreads();
        const float gg = ln1_g[colp], lb = ln1_b[colp];
#pragma unroll
        for (int rr = 0; rr < 4; ++rr) {
            const int row = 4 * g + rr;
            const float mu = red[0][row][0] * (1.0f / 256.0f);
            const float var = red[0][row][1] * (1.0f / 256.0f) - mu * mu;
            const float rs = rsqrtf(var + EPSF);
            const float yv = (vs[rr] - mu) * rs * gg + lb;
            ysum[(size_t)(t0 + row) * 256 + colp] = yv + vs[rr];
            Ytile[row * 264 + colp] = (ushort)f2bf(yv);
        }
    }
    __syncthreads();

    // ---- QKV: wave w -> cols [48w, 48w+48), 3 frags; weights preloaded
    //      8-deep per output-frag ----
    const ushort* wq = wb_qkv + (size_t)(wv * 48 + c) * 256 + g * 8;
    f32x4 accq[3] = {};
#pragma unroll
    for (int nf = 0; nf < 3; ++nf) {
        bf16x8 wf[8];
#pragma unroll
        for (int kc = 0; kc < 8; ++kc)
            wf[kc] = *(const bf16x8*)(wq + (size_t)nf * 4096 + kc * 32);
#pragma unroll
        for (int kc = 0; kc < 8; ++kc) {
            const bf16x8 af = *(const bf16x8*)&Ytile[c * 264 + kc * 32 + g * 8];
            accq[nf] = MFMA16(af, wf[kc], accq[nf]);
        }
    }
#pragma unroll
    for (int nf = 0; nf < 3; ++nf) {
        const int col = wv * 48 + nf * 16 + c;
        const float bb = bqs[col];
#pragma unroll
        for (int rr = 0; rr < 4; ++rr)
            qkvb[(size_t)(t0 + 4 * g + rr) * 768 + col] = (ushort)f2bf(accq[nf][rr] + bb);
    }
}

// ---------------------------------------------------------------------------
// Flash attention, FOUR Q-fragments per wave (64 queries/wave, 256/block),
// split-K over 2 HALVES (was 4 quarters): 4-Q freed the occupancy pressure
// (attn proven occupancy-insensitive R1/R2), so halving split-K cuts the
// partial-O round trip from 8MB to 4MB and Q re-reads from 4x to 2x, and
// fused_tail's combine drops to 2 load rounds. 32 iters per block.
// grid=(T/256, HEADS, 2) = 256 blocks (1/CU).
// ---------------------------------------------------------------------------
#define KS   40
#define VTS  72

__device__ __forceinline__ void qstep(
    const bf16x8 k0, const bf16x8 k1, const bf16x8 k2, const bf16x8 k3,
    const bf16x8 qf, const bf16x8 ones,
    const bf16x8 va0, const bf16x8 vb0, const bf16x8 va1, const bf16x8 vb1,
    f32x4& o0, f32x4& o1, f32x4& ol)
{
    const f32x4 zz = {0.f, 0.f, 0.f, 0.f};
    const f32x4 s0 = MFMA16(k0, qf, zz);
    const f32x4 s1 = MFMA16(k1, qf, zz);
    const f32x4 s2 = MFMA16(k2, qf, zz);
    const f32x4 s3 = MFMA16(k3, qf, zz);

    unsigned w00 = cvtpk_bf16(__builtin_amdgcn_exp2f(s0[0]), __builtin_amdgcn_exp2f(s0[1]));
    unsigned w01 = cvtpk_bf16(__builtin_amdgcn_exp2f(s0[2]), __builtin_amdgcn_exp2f(s0[3]));
    unsigned w10 = cvtpk_bf16(__builtin_amdgcn_exp2f(s1[0]), __builtin_amdgcn_exp2f(s1[1]));
    unsigned w11 = cvtpk_bf16(__builtin_amdgcn_exp2f(s1[2]), __builtin_amdgcn_exp2f(s1[3]));
    unsigned w20 = cvtpk_bf16(__builtin_amdgcn_exp2f(s2[0]), __builtin_amdgcn_exp2f(s2[1]));
    unsigned w21 = cvtpk_bf16(__builtin_amdgcn_exp2f(s2[2]), __builtin_amdgcn_exp2f(s2[3]));
    unsigned w30 = cvtpk_bf16(__builtin_amdgcn_exp2f(s3[0]), __builtin_amdgcn_exp2f(s3[1]));
    unsigned w31 = cvtpk_bf16(__builtin_amdgcn_exp2f(s3[2]), __builtin_amdgcn_exp2f(s3[3]));

    // in-register D->A relayout across lane groups g (bits 4-5)
    plswap32(w00, w10); plswap16(w00, w10);
    plswap32(w01, w11); plswap16(w01, w11);
    plswap32(w20, w30); plswap16(w20, w30);
    plswap32(w21, w31); plswap16(w21, w31);
    const uint4v u0 = {w00, w01, w10, w11};
    const uint4v u1 = {w20, w21, w30, w31};
    const bf16x8 pa0 = __builtin_bit_cast(bf16x8, u0);
    const bf16x8 pa1 = __builtin_bit_cast(bf16x8, u1);

    o0 = MFMA16(pa0, va0, o0);
    o1 = MFMA16(pa0, vb0, o1);
    ol = MFMA16(pa0, ones, ol);
    o0 = MFMA16(pa1, va1, o0);
    o1 = MFMA16(pa1, vb1, o1);
    ol = MFMA16(pa1, ones, ol);
}

__global__ __launch_bounds__(256) void attn_mfma(
    const ushort* __restrict__ qkv, ushort* __restrict__ o1,
    ushort* __restrict__ o2, float* __restrict__ lpart)
{
    const int h    = blockIdx.y;
    const int q0   = blockIdx.x << 8;        // 256 queries per block
    const int half = blockIdx.z;
    const int tid  = threadIdx.x;
    const int wv   = tid >> 6, lane = tid & 63;
    const int c    = lane & 15, g = lane >> 4;

    __shared__ ushort Ks[2][64 * KS];
    __shared__ ushort Vt[2][32 * VTS];

    const ushort* qbase = qkv + (size_t)(q0 + wv * 64 + c) * 768 + h * 32 + g * 8;
    const bf16x8 qfA = *(const bf16x8*)(qbase);
    const bf16x8 qfB = *(const bf16x8*)(qbase + 16 * 768);
    const bf16x8 qfC = *(const bf16x8*)(qbase + 32 * 768);
    const bf16x8 qfD = *(const bf16x8*)(qbase + 48 * 768);

    bf16x8 ones;
#pragma unroll
    for (int i = 0; i < 8; ++i) ones[i] = (short)0x3F80;

    f32x4 oA0 = {0.f,0.f,0.f,0.f}, oA1 = {0.f,0.f,0.f,0.f}, oAl = {0.f,0.f,0.f,0.f};
    f32x4 oB0 = {0.f,0.f,0.f,0.f}, oB1 = {0.f,0.f,0.f,0.f}, oBl = {0.f,0.f,0.f,0.f};
    f32x4 oC0 = {0.f,0.f,0.f,0.f}, oC1 = {0.f,0.f,0.f,0.f}, oCl = {0.f,0.f,0.f,0.f};
    f32x4 oD0 = {0.f,0.f,0.f,0.f}, oD1 = {0.f,0.f,0.f,0.f}, oDl = {0.f,0.f,0.f,0.f};

    const int kr = tid >> 2, kc = (tid & 3) * 8;
    const int vp = tid & 31, vd = (tid >> 5) * 4;
    const ushort* kbase = qkv + 256 + h * 32;
    const ushort* vbase = qkv + 512 + h * 32;

    const int kt0 = half * 32, kt1 = kt0 + 32;

    {   // prologue: stage tile kt0 directly into buf 0
        const ushort8 kv = *(const ushort8*)(kbase + ((size_t)kt0 * 64 + kr) * 768 + kc);
        const uint2v va = *(const uint2v*)(vbase + ((size_t)kt0 * 64 + 2 * vp) * 768 + vd);
        const uint2v vb = *(const uint2v*)(vbase + ((size_t)kt0 * 64 + 2 * vp + 1) * 768 + vd);
        *(ushort8*)&Ks[0][kr * KS + kc] = kv;
        unsigned* vtp = (unsigned*)&Vt[0][0];
        vtp[(vd + 0) * (VTS / 2) + vp] = __builtin_amdgcn_perm(vb.x, va.x, 0x05040100u);
        vtp[(vd + 1) * (VTS / 2) + vp] = __builtin_amdgcn_perm(vb.x, va.x, 0x07060302u);
        vtp[(vd + 2) * (VTS / 2) + vp] = __builtin_amdgcn_perm(vb.y, va.y, 0x05040100u);
        vtp[(vd + 3) * (VTS / 2) + vp] = __builtin_amdgcn_perm(vb.y, va.y, 0x07060302u);
    }
    // prefetch tile kt0+1 into regs
    ushort8 kpre = *(const ushort8*)(kbase + ((size_t)(kt0 + 1) * 64 + kr) * 768 + kc);
    uint2v vpre0 = *(const uint2v*)(vbase + ((size_t)(kt0 + 1) * 64 + 2 * vp) * 768 + vd);
    uint2v vpre1 = *(const uint2v*)(vbase + ((size_t)(kt0 + 1) * 64 + 2 * vp + 1) * 768 + vd);
    __syncthreads();

    int p = 0;
    for (int kt = kt0; kt < kt1; ++kt) {
        const ushort* ks = &Ks[p][0];
        const ushort* vt = &Vt[p][0];
        // K-frags and V-frags: read from LDS ONCE, reused for 4 Q-frags
        const bf16x8 k0 = *(const bf16x8*)&ks[(0 * 16 + c) * KS + g * 8];
        const bf16x8 k1 = *(const bf16x8*)&ks[(1 * 16 + c) * KS + g * 8];
        const bf16x8 k2 = *(const bf16x8*)&ks[(2 * 16 + c) * KS + g * 8];
        const bf16x8 k3 = *(const bf16x8*)&ks[(3 * 16 + c) * KS + g * 8];
        const bf16x8 va0 = *(const bf16x8*)&vt[(c)      * VTS + 0 * 32 + g * 8];
        const bf16x8 vb0 = *(const bf16x8*)&vt[(16 + c) * VTS + 0 * 32 + g * 8];
        const bf16x8 va1 = *(const bf16x8*)&vt[(c)      * VTS + 1 * 32 + g * 8];
        const bf16x8 vb1 = *(const bf16x8*)&vt[(16 + c) * VTS + 1 * 32 + g * 8];

        // stage tile kt+1 into the inactive buffer; prefetch kt+2
        if (kt + 1 < kt1) {
            *(ushort8*)&Ks[p ^ 1][kr * KS + kc] = kpre;
            unsigned* vtp = (unsigned*)&Vt[p ^ 1][0];
            vtp[(vd + 0) * (VTS / 2) + vp] = __builtin_amdgcn_perm(vpre1.x, vpre0.x, 0x05040100u);
            vtp[(vd + 1) * (VTS / 2) + vp] = __builtin_amdgcn_perm(vpre1.x, vpre0.x, 0x07060302u);
            vtp[(vd + 2) * (VTS / 2) + vp] = __builtin_amdgcn_perm(vpre1.y, vpre0.y, 0x05040100u);
            vtp[(vd + 3) * (VTS / 2) + vp] = __builtin_amdgcn_perm(vpre1.y, vpre0.y, 0x07060302u);
            if (kt + 2 < kt1) {
                const size_t t2 = (size_t)(kt + 2) * 64;
                kpre  = *(const ushort8*)(kbase + (t2 + kr) * 768 + kc);
                vpre0 = *(const uint2v*)(vbase + (t2 + 2 * vp) * 768 + vd);
                vpre1 = *(const uint2v*)(vbase + (t2 + 2 * vp + 1) * 768 + vd);
            }
        }

        qstep(k0, k1, k2, k3, qfA, ones, va0, vb0, va1, vb1, oA0, oA1, oAl);
        qstep(k0, k1, k2, k3, qfB, ones, va0, vb0, va1, vb1, oB0, oB1, oBl);
        qstep(k0, k1, k2, k3, qfC, ones, va0, vb0, va1, vb1, oC0, oC1, oCl);
        qstep(k0, k1, k2, k3, qfD, ones, va0, vb0, va1, vb1, oD0, oD1, oDl);

        p ^= 1;
        __syncthreads();   // single barrier per K-tile
    }

    {
        ushort* ob = half ? o2 : o1;
        ushort* op = ob + (size_t)(q0 + wv * 64) * 256 + h * 32;
#pragma unroll
        for (int rr = 0; rr < 4; ++rr) {
            op[( 0 + 4 * g + rr) * 256 + c]      = (ushort)f2bf(oA0[rr]);
            op[( 0 + 4 * g + rr) * 256 + 16 + c] = (ushort)f2bf(oA1[rr]);
            op[(16 + 4 * g + rr) * 256 + c]      = (ushort)f2bf(oB0[rr]);
            op[(16 + 4 * g + rr) * 256 + 16 + c] = (ushort)f2bf(oB1[rr]);
            op[(32 + 4 * g + rr) * 256 + c]      = (ushort)f2bf(oC0[rr]);
            op[(32 + 4 * g + rr) * 256 + 16 + c] = (ushort)f2bf(oC1[rr]);
            op[(48 + 4 * g + rr) * 256 + c]      = (ushort)f2bf(oD0[rr]);
            op[(48 + 4 * g + rr) * 256 + 16 + c] = (ushort)f2bf(oD1[rr]);
        }
        if (c == 0) {
            float* lp = lpart + (size_t)(q0 + wv * 64) * 16 + half * 8 + h;
#pragma unroll
            for (int rr = 0; rr < 4; ++rr) {
                lp[(size_t)( 0 + 4 * g + rr) * 16] = oAl[rr];
                lp[(size_t)(16 + 4 * g + rr) * 16] = oBl[rr];
                lp[(size_t)(32 + 4 * g + rr) * 16] = oCl[rr];
                lp[(size_t)(48 + 4 * g + rr) * 16] = oDl[rr];
            }
        }
    }
}

// ---------------------------------------------------------------------------
// Fused tail: combine O halves + attn-proj + LN2 + FF1(gelu) + FF2 +
// proj_out. grid 256, block 1024 (16 waves), 16 tokens per block — the
// weight-read-path optimum (R11's 2-block/CU split doubled weight traffic
// and doubled time). Combine reads 2 halves (was 4 quarters). LDS 60.4 KB.
// ---------------------------------------------------------------------------
__global__ __launch_bounds__(1024, 4) void fused_tail(
    const ushort* __restrict__ o1, const ushort* __restrict__ o2,
    const float* __restrict__ lpart, const ushort* __restrict__ wb_ap,
    const float* __restrict__ b_ap, const float* __restrict__ ysum,
    const float* __restrict__ ln2_g, const float* __restrict__ ln2_b,
    const ushort* __restrict__ wb_ff1, const float* __restrict__ b_ff1,
    const ushort* __restrict__ wb_ff2, const float* __restrict__ b_ff2,
    const ushort* __restrict__ wb_out, const float* __restrict__ b_out,
    const float* __restrict__ x, float* __restrict__ out)
{
    __shared__ ushort Otile[16 * 264];
    __shared__ ushort Ztile[16 * 264];
    __shared__ ushort Zbig[16 * 1032];
    __shared__ ushort T2tile[16 * 264];
    __shared__ float  red[16][16][2];
    const int t0 = blockIdx.x * 16;
    const int tid = threadIdx.x, wv = tid >> 6, lane = tid & 63;
    const int c = lane & 15, g = lane >> 4;
    const int colp = wv * 16 + c;

    // early: preload attn-proj weight frags (global, no dependencies)
    bf16x8 wap[8];
    {
        const ushort* wp = wb_ap + (size_t)colp * 256 + g * 8;
#pragma unroll
        for (int kc = 0; kc < 8; ++kc) wap[kc] = *(const bf16x8*)(wp + kc * 32);
    }

    {   // combine O halves (ushort4 per thread)
        const int r = tid >> 6, c0 = (tid & 63) * 4;
        const int h = (tid & 63) >> 3;   // c0>>5: head of these 4 channels
        const float* lp = lpart + (size_t)(t0 + r) * 16;
        const float inv = 1.0f / (lp[h] + lp[8 + h]);
        const size_t idx = (size_t)(t0 + r) * 256 + c0;
        const ushort4 a = *(const ushort4*)(o1 + idx);
        const ushort4 b = *(const ushort4*)(o2 + idx);
        unsigned w[2];
        w[0] = pk_bf16((bf2f(a.x) + bf2f(b.x)) * inv, (bf2f(a.y) + bf2f(b.y)) * inv);
        w[1] = pk_bf16((bf2f(a.z) + bf2f(b.z)) * inv, (bf2f(a.w) + bf2f(b.w)) * inv);
        *(ushort4*)&Otile[r * 264 + c0] = *(ushort4*)w;
    }
    // issue ysum loads early — consumed after the AP-MFMA phase (T14)
    float ysv[4];
#pragma unroll
    for (int rr = 0; rr < 4; ++rr)
        ysv[rr] = ysum[(size_t)(t0 + 4 * g + rr) * 256 + colp];
    __syncthreads();

    // ---- attn-proj: wave w -> cols [16w,16w+16), one frag ----
    f32x4 accp = {};
#pragma unroll
    for (int kc = 0; kc < 8; ++kc) {
        const bf16x8 af = *(const bf16x8*)&Otile[c * 264 + kc * 32 + g * 8];
        accp = MFMA16(af, wap[kc], accp);
    }
    float vsave[4];
    {
        const float bb = b_ap[colp];
        float s1[4], s2[4];
#pragma unroll
        for (int rr = 0; rr < 4; ++rr) {
            const float v = accp[rr] + bb + ysv[rr];
            vsave[rr] = v; s1[rr] = v; s2[rr] = v * v;
        }
#pragma unroll
        for (int rr = 0; rr < 4; ++rr) { s1[rr] = rowsum16(s1[rr]); s2[rr] = rowsum16(s2[rr]); }
        if (c == 0) {
#pragma unroll
            for (int rr = 0; rr < 4; ++rr) {
                red[wv][4 * g + rr][0] = s1[rr];
                red[wv][4 * g + rr][1] = s2[rr];
            }
        }
        __syncthreads();
        if (tid < 32) {
            const int row = tid >> 1, j = tid & 1;
            float s = 0.f;
#pragma unroll
            for (int w = 0; w < 16; ++w) s += red[w][row][j];
            red[0][row][j] = s;
        }
        __syncthreads();
        const float gg = ln2_g[colp], lb = ln2_b[colp];
#pragma unroll
        for (int rr = 0; rr < 4; ++rr) {
            const int row = 4 * g + rr;
            const float mu = red[0][row][0] * (1.0f / 256.0f);
            const float var = red[0][row][1] * (1.0f / 256.0f) - mu * mu;
            const float rs = rsqrtf(var + EPSF);
            const float zv = (vsave[rr] - mu) * rs * gg + lb;
            Ztile[row * 264 + colp] = (ushort)f2bf(zv);
        }
    }
    __syncthreads();

    // ---- FF1 + gelu: wave w -> cols [64w,64w+64); weights preloaded 8-deep
    //      per output-frag (one L2 latency per nf) ----
    {
        const ushort* wf1 = wb_ff1 + (size_t)(wv * 64 + c) * 256 + g * 8;
        f32x4 accf[4] = {};
#pragma unroll
        for (int nf = 0; nf < 4; ++nf) {
            bf16x8 wf[8];
#pragma unroll
            for (int kc = 0; kc < 8; ++kc)
                wf[kc] = *(const bf16x8*)(wf1 + (size_t)nf * 4096 + kc * 32);
#pragma unroll
            for (int kc = 0; kc < 8; ++kc) {
                const bf16x8 af = *(const bf16x8*)&Ztile[c * 264 + kc * 32 + g * 8];
                accf[nf] = MFMA16(af, wf[kc], accf[nf]);
            }
        }
#pragma unroll
        for (int nf = 0; nf < 4; ++nf) {
            const int col = wv * 64 + nf * 16 + c;
            const float bb = b_ff1[col];
#pragma unroll
            for (int rr = 0; rr < 4; ++rr) {
                const float v = gelu_f(accf[nf][rr] + bb);
                Zbig[(4 * g + rr) * 1032 + col] = (ushort)f2bf(v);
            }
        }
    }
    __syncthreads();

    // ---- FF2: K=1024, weights preloaded 8-deep per chunk, 2 acc chains ----
    {
        const ushort* wf2 = wb_ff2 + (size_t)colp * 1024 + g * 8;
        f32x4 acc0 = {}, acc1 = {};
#pragma unroll
        for (int ch = 0; ch < 4; ++ch) {
            bf16x8 wf[8];
#pragma unroll
            for (int kk = 0; kk < 8; ++kk)
                wf[kk] = *(const bf16x8*)(wf2 + (ch * 8 + kk) * 32);
#pragma unroll
            for (int kk = 0; kk < 8; ++kk) {
                const int kc = ch * 8 + kk;
                const bf16x8 af = *(const bf16x8*)&Zbig[c * 1032 + kc * 32 + g * 8];
                if (kk & 1) acc1 = MFMA16(af, wf[kk], acc1);
                else        acc0 = MFMA16(af, wf[kk], acc0);
            }
        }
        const float bb = b_ff2[colp];
#pragma unroll
        for (int rr = 0; rr < 4; ++rr) {
            const float v = acc0[rr] + acc1[rr] + bb + vsave[rr];
            T2tile[(4 * g + rr) * 264 + colp] = (ushort)f2bf(v);
        }
    }
    // preload proj_out weights + x residual before the last barrier (T14)
    bf16x8 wout[8];
    {
        const ushort* wo = wb_out + (size_t)colp * 256 + g * 8;
#pragma unroll
        for (int kc = 0; kc < 8; ++kc) wout[kc] = *(const bf16x8*)(wo + kc * 32);
    }
    float xres[4];
#pragma unroll
    for (int rr = 0; rr < 4; ++rr)
        xres[rr] = x[(size_t)(wv * 16 + 4 * g + rr) * T_TOK + t0 + c];
    __syncthreads();

    // ---- proj_out: wave w -> out rows [16w,16w+16) ----
    f32x4 acco = {};
#pragma unroll
    for (int kc = 0; kc < 8; ++kc) {
        const bf16x8 bfr = *(const bf16x8*)&T2tile[c * 264 + kc * 32 + g * 8]; // B: token=c
        acco = MFMA16(wout[kc], bfr, acco);
    }
#pragma unroll
    for (int rr = 0; rr < 4; ++rr) {
        const int och = wv * 16 + 4 * g + rr;
        const size_t idx = (size_t)och * T_TOK + t0 + c;
        out[idx] = acco[rr] + b_out[och] + xres[rr];
    }
}

// ---------------------------------------------------------------------------
extern "C" void kernel_launch(void* const* d_in, const int* in_sizes, int n_in,
                              void* d_out, int out_size, void* d_ws, size_t ws_size,
                              hipStream_t stream)
{
    const float* x     = (const float*)d_in[0];
    const float* bn_g  = (const float*)d_in[1];
    const float* bn_b  = (const float*)d_in[2];
    const float* bn_m  = (const float*)d_in[3];
    const float* bn_v  = (const float*)d_in[4];
    const float* w_in  = (const float*)d_in[5];
    const float* b_in  = (const float*)d_in[6];
    const float* ln1_g = (const float*)d_in[7];
    const float* ln1_b = (const float*)d_in[8];
    const float* w_qkv = (const float*)d_in[9];
    const float* b_qkv = (const float*)d_in[10];
    const float* w_ap  = (const float*)d_in[11];
    const float* b_ap  = (const float*)d_in[12];
    const float* ln2_g = (const float*)d_in[13];
    const float* ln2_b = (const float*)d_in[14];
    const float* w_ff1 = (const float*)d_in[15];
    const float* b_ff1 = (const float*)d_in[16];
    const float* w_ff2 = (const float*)d_in[17];
    const float* b_ff2 = (const float*)d_in[18];
    const float* w_out = (const float*)d_in[19];
    const float* b_out = (const float*)d_in[20];
    float* out = (float*)d_out;
    float* ws  = (float*)d_ws;

    const size_t MF = 1u << 20;   // 1M f32 = 4 MB
    float*  ysum   = ws + MF;                           // [1M,2M)
    ushort* qkv_bf = (ushort*)(ws + 3 * MF);            // [3M,4.5M)
    ushort* o1p    = (ushort*)(ws + 6 * MF + MF / 2);   // [6.5M,7M)
    ushort* o2p    = (ushort*)(ws + 7 * MF);            // [7M,7.5M)
    float*  lpart  = ws + 8 * MF + MF / 2;              // [8.5M,+64K f32 = 256KB)
    ushort* wbuf   = (ushort*)(ws + 8 * MF + MF / 2 + 131072);  // weight arena
    const ushort* wb_in  = wbuf;
    const ushort* wb_qkv = wbuf + 65536;
    const ushort* wb_ap  = wbuf + 262144;
    const ushort* wb_ff1 = wbuf + 327680;
    const ushort* wb_ff2 = wbuf + 589824;
    const ushort* wb_out = wbuf + 851968;
    float* bqs = (float*)(wbuf + 917504);

    prep_kernel<<<896, 256, 0, stream>>>(w_in, w_qkv, w_ap, w_ff1, w_ff2, w_out,
                                         b_qkv, wbuf, bqs);
    fused_pre<<<256, 1024, 0, stream>>>(x, bn_g, bn_b, bn_m, bn_v,
                                        wb_in, b_in, ln1_g, ln1_b,
                                        wb_qkv, bqs, ysum, qkv_bf);
    attn_mfma<<<dim3(16, 8, 2), 256, 0, stream>>>(qkv_bf, o1p, o2p, lpart);
    fused_tail<<<256, 1024, 0, stream>>>(o1p, o2p, lpart, wb_ap, b_ap,
                                         ysum, ln2_g, ln2_b, wb_ff1, b_ff1,
                                         wb_ff2, b_ff2, wb_out, b_out, x, out);
}

// Round 14
// 187.757 us; speedup vs baseline: 1.0140x; 1.0140x over previous
//
#include <hip/hip_runtime.h>
#include <math.h>

#define T_TOK 4096
#define C_DIM 256
#define EPSF  1e-5f
// hd^-0.5 * log2(e): folded into q-projection weights/bias -> scores in log2 domain
#define SC_QL (0.17677669529663687f * 1.4426950408889634f)
// pin instruction order: stop the scheduler from sinking preloads past this
#define SBAR() __builtin_amdgcn_sched_barrier(0)

typedef short  bf16x8  __attribute__((ext_vector_type(8)));
typedef float  f32x4   __attribute__((ext_vector_type(4)));
typedef ushort ushort8 __attribute__((ext_vector_type(8)));
typedef unsigned uint4v __attribute__((ext_vector_type(4)));
typedef unsigned uint2v __attribute__((ext_vector_type(2)));

__device__ __forceinline__ short f2bf(float f) {
    unsigned u = __builtin_bit_cast(unsigned, f);
    unsigned r = (u + 0x7FFFu + ((u >> 16) & 1u)) >> 16;
    return (short)r;
}
__device__ __forceinline__ float bf2f(ushort u) {
    return __builtin_bit_cast(float, ((unsigned)u) << 16);
}
// pack two f32 -> bf16 pair (a=low, b=high), round-half-up via v_perm
__device__ __forceinline__ unsigned pk_bf16(float a, float b) {
    const unsigned ua = __builtin_bit_cast(unsigned, a) + 0x8000u;
    const unsigned ub = __builtin_bit_cast(unsigned, b) + 0x8000u;
    return __builtin_amdgcn_perm(ub, ua, 0x07060302u);
}
// single-instruction pack (RNE) for the attention P-matrix
__device__ __forceinline__ unsigned cvtpk_bf16(float a, float b) {
    unsigned r;
    asm("v_cvt_pk_bf16_f32 %0, %1, %2" : "=v"(r) : "v"(a), "v"(b));
    return r;
}
// gfx950 dual-dest lane-group swaps (exchange across lane bit 5 / bit 4)
__device__ __forceinline__ void plswap32(unsigned &a, unsigned &b) {
    asm("v_permlane32_swap_b32 %0, %1" : "+v"(a), "+v"(b));
}
__device__ __forceinline__ void plswap16(unsigned &a, unsigned &b) {
    asm("v_permlane16_swap_b32 %0, %1" : "+v"(a), "+v"(b));
}
template <int CTRL>
__device__ __forceinline__ float dppf(float x) {
    return __builtin_bit_cast(float,
        __builtin_amdgcn_mov_dpp(__builtin_bit_cast(int, x), CTRL, 0xF, 0xF, true));
}
__device__ __forceinline__ float rowsum16(float x) {
    x += dppf<0xB1>(x);
    x += dppf<0x4E>(x);
    x += dppf<0x141>(x);
    x += dppf<0x140>(x);
    return x;
}
// gelu, tanh form via exp2+rcp: v*t/(t+1), t=exp2(v*(2.302208+0.1029431 v^2))
__device__ __forceinline__ float gelu_f(float v) {
    const float u  = v * v;
    const float w2 = fmaf(u, 0.10294310f, 2.30220800f);
    const float t  = __builtin_amdgcn_exp2f(v * w2);
    return v * t * __builtin_amdgcn_rcpf(t + 1.0f);
}
#define MFMA16(a, b, c) __builtin_amdgcn_mfma_f32_16x16x32_bf16(a, b, c, 0, 0, 0)

// ---------------------------------------------------------------------------
// prep: weights f32->bf16 arena only (q-rows of w_qkv/b_qkv scaled). grid 896.
// ---------------------------------------------------------------------------
__global__ __launch_bounds__(256) void prep_kernel(
    const float* __restrict__ w_in, const float* __restrict__ w_qkv,
    const float* __restrict__ w_ap, const float* __restrict__ w_ff1,
    const float* __restrict__ w_ff2, const float* __restrict__ w_out,
    const float* __restrict__ b_qkv, ushort* __restrict__ wbuf,
    float* __restrict__ bqs)
{
    const int gid = blockIdx.x * 256 + threadIdx.x;
    const int e0 = gid * 4;
    const float* src; int off; float sc = 1.f;
    if (e0 < 65536)       { src = w_in;  off = e0; }
    else if (e0 < 262144) { src = w_qkv; off = e0 - 65536; if (off < 65536) sc = SC_QL; }
    else if (e0 < 327680) { src = w_ap;  off = e0 - 262144; }
    else if (e0 < 589824) { src = w_ff1; off = e0 - 327680; }
    else if (e0 < 851968) { src = w_ff2; off = e0 - 589824; }
    else                  { src = w_out; off = e0 - 851968; }
    const float4 v = *(const float4*)(src + off);
    ushort4 o;
    o.x = (ushort)f2bf(v.x * sc); o.y = (ushort)f2bf(v.y * sc);
    o.z = (ushort)f2bf(v.z * sc); o.w = (ushort)f2bf(v.w * sc);
    *(ushort4*)(wbuf + e0) = o;
    if (gid < 192) {
        const float s2 = (gid < 64) ? SC_QL : 1.f;
        float4 b = ((const float4*)b_qkv)[gid];
        b.x *= s2; b.y *= s2; b.z *= s2; b.w *= s2;
        ((float4*)bqs)[gid] = b;
    }
}

// ---------------------------------------------------------------------------
// Fused pre-attention: BN + proj_in + LN1 + QKV. grid 256, block 1024
// (16 waves), 16 tokens per block. Weight preloads pinned 8-deep with
// sched_barrier(0) — without the fence the compiler sinks the loads back to
// their uses (R10/R12 showed VGPR stuck at 40), re-serializing ~20 L2
// latency rounds per phase.
// ---------------------------------------------------------------------------
__global__ __launch_bounds__(1024, 4) void fused_pre(
    const float* __restrict__ x, const float* __restrict__ bn_g,
    const float* __restrict__ bn_b, const float* __restrict__ bn_m,
    const float* __restrict__ bn_v,
    const ushort* __restrict__ wb_in, const float* __restrict__ b_in,
    const float* __restrict__ ln1_g, const float* __restrict__ ln1_b,
    const ushort* __restrict__ wb_qkv, const float* __restrict__ bqs,
    float* __restrict__ ysum, ushort* __restrict__ qkvb)
{
    __shared__ ushort Atile[16 * 264];
    __shared__ ushort Ytile[16 * 264];
    __shared__ float  red[16][16][2];
    const int t0 = blockIdx.x * 16;
    const int tid = threadIdx.x, wv = tid >> 6, lane = tid & 63;
    const int c = lane & 15, g = lane >> 4;
    const int colp = wv * 16 + c;

    // early: preload proj_in weight frags (pinned — must issue before BN)
    bf16x8 win[8];
    {
        const ushort* wp = wb_in + (size_t)colp * 256 + g * 8;
#pragma unroll
        for (int kc = 0; kc < 8; ++kc) win[kc] = *(const bf16x8*)(wp + kc * 32);
    }
    SBAR();

    {   // BN + transpose: thread (cc, tt-group) reads 4 t of channel cc
        const int cc = tid >> 2;            // 0..255
        const int tt = (tid & 3) * 4;       // 0,4,8,12
        const float a = rsqrtf(bn_v[cc] + EPSF) * bn_g[cc];
        const float d = bn_b[cc] - bn_m[cc] * a;
        const float4 v = *(const float4*)(x + (size_t)cc * T_TOK + t0 + tt);
        Atile[(tt + 0) * 264 + cc] = (ushort)f2bf(fmaf(v.x, a, d));
        Atile[(tt + 1) * 264 + cc] = (ushort)f2bf(fmaf(v.y, a, d));
        Atile[(tt + 2) * 264 + cc] = (ushort)f2bf(fmaf(v.z, a, d));
        Atile[(tt + 3) * 264 + cc] = (ushort)f2bf(fmaf(v.w, a, d));
    }
    __syncthreads();

    // ---- proj_in: wave w -> cols [16w, 16w+16), one frag ----
    f32x4 accp = {};
#pragma unroll
    for (int kc = 0; kc < 8; ++kc) {
        const bf16x8 af = *(const bf16x8*)&Atile[c * 264 + kc * 32 + g * 8];
        accp = MFMA16(af, win[kc], accp);
    }
    {
        const float bb = b_in[colp];
        float vs[4], s1[4], s2[4];
#pragma unroll
        for (int rr = 0; rr < 4; ++rr) {
            const float v = accp[rr] + bb;
            vs[rr] = v; s1[rr] = v; s2[rr] = v * v;
        }
#pragma unroll
        for (int rr = 0; rr < 4; ++rr) { s1[rr] = rowsum16(s1[rr]); s2[rr] = rowsum16(s2[rr]); }
        if (c == 0) {
#pragma unroll
            for (int rr = 0; rr < 4; ++rr) {
                red[wv][4 * g + rr][0] = s1[rr];
                red[wv][4 * g + rr][1] = s2[rr];
            }
        }
        __syncthreads();
        if (tid < 32) {   // stage-2 reduce across 16 waves
            const int row = tid >> 1, j = tid & 1;
            float s = 0.f;
#pragma unroll
            for (int w = 0; w < 16; ++w) s += red[w][row][j];
            red[0][row][j] = s;
        }
        __syncthreads();
        const float gg = ln1_g[colp], lb = ln1_b[colp];
#pragma unroll
        for (int rr = 0; rr < 4; ++rr) {
            const int row = 4 * g + rr;
            const float mu = red[0][row][0] * (1.0f / 256.0f);
            const float var = red[0][row][1] * (1.0f / 256.0f) - mu * mu;
            const float rs = rsqrtf(var + EPSF);
            const float yv = (vs[rr] - mu) * rs * gg + lb;
            ysum[(size_t)(t0 + row) * 256 + colp] = yv + vs[rr];
            Ytile[row * 264 + colp] = (ushort)f2bf(yv);
        }
    }
    __syncthreads();

    // ---- QKV: wave w -> cols [48w, 48w+48), 3 frags; weights preloaded
    //      8-deep per output-frag, load group pinned ----
    const ushort* wq = wb_qkv + (size_t)(wv * 48 + c) * 256 + g * 8;
    f32x4 accq[3] = {};
#pragma unroll
    for (int nf = 0; nf < 3; ++nf) {
        bf16x8 wf[8];
#pragma unroll
        for (int kc = 0; kc < 8; ++kc)
            wf[kc] = *(const bf16x8*)(wq + (size_t)nf * 4096 + kc * 32);
        SBAR();
#pragma unroll
        for (int kc = 0; kc < 8; ++kc) {
            const bf16x8 af = *(const bf16x8*)&Ytile[c * 264 + kc * 32 + g * 8];
            accq[nf] = MFMA16(af, wf[kc], accq[nf]);
        }
    }
#pragma unroll
    for (int nf = 0; nf < 3; ++nf) {
        const int col = wv * 48 + nf * 16 + c;
        const float bb = bqs[col];
#pragma unroll
        for (int rr = 0; rr < 4; ++rr)
            qkvb[(size_t)(t0 + 4 * g + rr) * 768 + col] = (ushort)f2bf(accq[nf][rr] + bb);
    }
}

// ---------------------------------------------------------------------------
// Flash attention (R12-exact, measured best): FOUR Q-fragments per wave
// (64 queries/wave, 256/block), split-K over 4 quarters. K/V frags read
// from LDS once per iteration, reused 4x. K+V LDS double-buffered,
// kr=tid>>2 coalesced staging, v_perm V-pack, single barrier per K-tile.
// grid=(T/256, HEADS, 4) = 512 blocks (2/CU). R13's split-K=2 regressed
// attn by ~3us (longer serial loop) — reverted.
// ---------------------------------------------------------------------------
#define KS   40
#define VTS  72

__device__ __forceinline__ void qstep(
    const bf16x8 k0, const bf16x8 k1, const bf16x8 k2, const bf16x8 k3,
    const bf16x8 qf, const bf16x8 ones,
    const bf16x8 va0, const bf16x8 vb0, const bf16x8 va1, const bf16x8 vb1,
    f32x4& o0, f32x4& o1, f32x4& ol)
{
    const f32x4 zz = {0.f, 0.f, 0.f, 0.f};
    const f32x4 s0 = MFMA16(k0, qf, zz);
    const f32x4 s1 = MFMA16(k1, qf, zz);
    const f32x4 s2 = MFMA16(k2, qf, zz);
    const f32x4 s3 = MFMA16(k3, qf, zz);

    unsigned w00 = cvtpk_bf16(__builtin_amdgcn_exp2f(s0[0]), __builtin_amdgcn_exp2f(s0[1]));
    unsigned w01 = cvtpk_bf16(__builtin_amdgcn_exp2f(s0[2]), __builtin_amdgcn_exp2f(s0[3]));
    unsigned w10 = cvtpk_bf16(__builtin_amdgcn_exp2f(s1[0]), __builtin_amdgcn_exp2f(s1[1]));
    unsigned w11 = cvtpk_bf16(__builtin_amdgcn_exp2f(s1[2]), __builtin_amdgcn_exp2f(s1[3]));
    unsigned w20 = cvtpk_bf16(__builtin_amdgcn_exp2f(s2[0]), __builtin_amdgcn_exp2f(s2[1]));
    unsigned w21 = cvtpk_bf16(__builtin_amdgcn_exp2f(s2[2]), __builtin_amdgcn_exp2f(s2[3]));
    unsigned w30 = cvtpk_bf16(__builtin_amdgcn_exp2f(s3[0]), __builtin_amdgcn_exp2f(s3[1]));
    unsigned w31 = cvtpk_bf16(__builtin_amdgcn_exp2f(s3[2]), __builtin_amdgcn_exp2f(s3[3]));

    // in-register D->A relayout across lane groups g (bits 4-5)
    plswap32(w00, w10); plswap16(w00, w10);
    plswap32(w01, w11); plswap16(w01, w11);
    plswap32(w20, w30); plswap16(w20, w30);
    plswap32(w21, w31); plswap16(w21, w31);
    const uint4v u0 = {w00, w01, w10, w11};
    const uint4v u1 = {w20, w21, w30, w31};
    const bf16x8 pa0 = __builtin_bit_cast(bf16x8, u0);
    const bf16x8 pa1 = __builtin_bit_cast(bf16x8, u1);

    o0 = MFMA16(pa0, va0, o0);
    o1 = MFMA16(pa0, vb0, o1);
    ol = MFMA16(pa0, ones, ol);
    o0 = MFMA16(pa1, va1, o0);
    o1 = MFMA16(pa1, vb1, o1);
    ol = MFMA16(pa1, ones, ol);
}

__global__ __launch_bounds__(256) void attn_mfma(
    const ushort* __restrict__ qkv, ushort* __restrict__ o1,
    ushort* __restrict__ o2, ushort* __restrict__ o3,
    ushort* __restrict__ o4, float* __restrict__ lpart)
{
    const int h    = blockIdx.y;
    const int q0   = blockIdx.x << 8;        // 256 queries per block
    const int qrt  = blockIdx.z;
    const int tid  = threadIdx.x;
    const int wv   = tid >> 6, lane = tid & 63;
    const int c    = lane & 15, g = lane >> 4;

    __shared__ ushort Ks[2][64 * KS];
    __shared__ ushort Vt[2][32 * VTS];

    const ushort* qbase = qkv + (size_t)(q0 + wv * 64 + c) * 768 + h * 32 + g * 8;
    const bf16x8 qfA = *(const bf16x8*)(qbase);
    const bf16x8 qfB = *(const bf16x8*)(qbase + 16 * 768);
    const bf16x8 qfC = *(const bf16x8*)(qbase + 32 * 768);
    const bf16x8 qfD = *(const bf16x8*)(qbase + 48 * 768);

    bf16x8 ones;
#pragma unroll
    for (int i = 0; i < 8; ++i) ones[i] = (short)0x3F80;

    f32x4 oA0 = {0.f,0.f,0.f,0.f}, oA1 = {0.f,0.f,0.f,0.f}, oAl = {0.f,0.f,0.f,0.f};
    f32x4 oB0 = {0.f,0.f,0.f,0.f}, oB1 = {0.f,0.f,0.f,0.f}, oBl = {0.f,0.f,0.f,0.f};
    f32x4 oC0 = {0.f,0.f,0.f,0.f}, oC1 = {0.f,0.f,0.f,0.f}, oCl = {0.f,0.f,0.f,0.f};
    f32x4 oD0 = {0.f,0.f,0.f,0.f}, oD1 = {0.f,0.f,0.f,0.f}, oDl = {0.f,0.f,0.f,0.f};

    const int kr = tid >> 2, kc = (tid & 3) * 8;
    const int vp = tid & 31, vd = (tid >> 5) * 4;
    const ushort* kbase = qkv + 256 + h * 32;
    const ushort* vbase = qkv + 512 + h * 32;

    const int kt0 = qrt * 16, kt1 = kt0 + 16;

    {   // prologue: stage tile kt0 directly into buf 0
        const ushort8 kv = *(const ushort8*)(kbase + ((size_t)kt0 * 64 + kr) * 768 + kc);
        const uint2v va = *(const uint2v*)(vbase + ((size_t)kt0 * 64 + 2 * vp) * 768 + vd);
        const uint2v vb = *(const uint2v*)(vbase + ((size_t)kt0 * 64 + 2 * vp + 1) * 768 + vd);
        *(ushort8*)&Ks[0][kr * KS + kc] = kv;
        unsigned* vtp = (unsigned*)&Vt[0][0];
        vtp[(vd + 0) * (VTS / 2) + vp] = __builtin_amdgcn_perm(vb.x, va.x, 0x05040100u);
        vtp[(vd + 1) * (VTS / 2) + vp] = __builtin_amdgcn_perm(vb.x, va.x, 0x07060302u);
        vtp[(vd + 2) * (VTS / 2) + vp] = __builtin_amdgcn_perm(vb.y, va.y, 0x05040100u);
        vtp[(vd + 3) * (VTS / 2) + vp] = __builtin_amdgcn_perm(vb.y, va.y, 0x07060302u);
    }
    // prefetch tile kt0+1 into regs
    ushort8 kpre = *(const ushort8*)(kbase + ((size_t)(kt0 + 1) * 64 + kr) * 768 + kc);
    uint2v vpre0 = *(const uint2v*)(vbase + ((size_t)(kt0 + 1) * 64 + 2 * vp) * 768 + vd);
    uint2v vpre1 = *(const uint2v*)(vbase + ((size_t)(kt0 + 1) * 64 + 2 * vp + 1) * 768 + vd);
    __syncthreads();

    int p = 0;
    for (int kt = kt0; kt < kt1; ++kt) {
        const ushort* ks = &Ks[p][0];
        const ushort* vt = &Vt[p][0];
        // K-frags and V-frags: read from LDS ONCE, reused for 4 Q-frags
        const bf16x8 k0 = *(const bf16x8*)&ks[(0 * 16 + c) * KS + g * 8];
        const bf16x8 k1 = *(const bf16x8*)&ks[(1 * 16 + c) * KS + g * 8];
        const bf16x8 k2 = *(const bf16x8*)&ks[(2 * 16 + c) * KS + g * 8];
        const bf16x8 k3 = *(const bf16x8*)&ks[(3 * 16 + c) * KS + g * 8];
        const bf16x8 va0 = *(const bf16x8*)&vt[(c)      * VTS + 0 * 32 + g * 8];
        const bf16x8 vb0 = *(const bf16x8*)&vt[(16 + c) * VTS + 0 * 32 + g * 8];
        const bf16x8 va1 = *(const bf16x8*)&vt[(c)      * VTS + 1 * 32 + g * 8];
        const bf16x8 vb1 = *(const bf16x8*)&vt[(16 + c) * VTS + 1 * 32 + g * 8];

        // stage tile kt+1 into the inactive buffer; prefetch kt+2
        if (kt + 1 < kt1) {
            *(ushort8*)&Ks[p ^ 1][kr * KS + kc] = kpre;
            unsigned* vtp = (unsigned*)&Vt[p ^ 1][0];
            vtp[(vd + 0) * (VTS / 2) + vp] = __builtin_amdgcn_perm(vpre1.x, vpre0.x, 0x05040100u);
            vtp[(vd + 1) * (VTS / 2) + vp] = __builtin_amdgcn_perm(vpre1.x, vpre0.x, 0x07060302u);
            vtp[(vd + 2) * (VTS / 2) + vp] = __builtin_amdgcn_perm(vpre1.y, vpre0.y, 0x05040100u);
            vtp[(vd + 3) * (VTS / 2) + vp] = __builtin_amdgcn_perm(vpre1.y, vpre0.y, 0x07060302u);
            if (kt + 2 < kt1) {
                const size_t t2 = (size_t)(kt + 2) * 64;
                kpre  = *(const ushort8*)(kbase + (t2 + kr) * 768 + kc);
                vpre0 = *(const uint2v*)(vbase + (t2 + 2 * vp) * 768 + vd);
                vpre1 = *(const uint2v*)(vbase + (t2 + 2 * vp + 1) * 768 + vd);
            }
        }

        qstep(k0, k1, k2, k3, qfA, ones, va0, vb0, va1, vb1, oA0, oA1, oAl);
        qstep(k0, k1, k2, k3, qfB, ones, va0, vb0, va1, vb1, oB0, oB1, oBl);
        qstep(k0, k1, k2, k3, qfC, ones, va0, vb0, va1, vb1, oC0, oC1, oCl);
        qstep(k0, k1, k2, k3, qfD, ones, va0, vb0, va1, vb1, oD0, oD1, oDl);

        p ^= 1;
        __syncthreads();   // single barrier per K-tile
    }

    {
        ushort* ob = (qrt & 2) ? ((qrt & 1) ? o4 : o3) : ((qrt & 1) ? o2 : o1);
        ushort* op = ob + (size_t)(q0 + wv * 64) * 256 + h * 32;
#pragma unroll
        for (int rr = 0; rr < 4; ++rr) {
            op[( 0 + 4 * g + rr) * 256 + c]      = (ushort)f2bf(oA0[rr]);
            op[( 0 + 4 * g + rr) * 256 + 16 + c] = (ushort)f2bf(oA1[rr]);
            op[(16 + 4 * g + rr) * 256 + c]      = (ushort)f2bf(oB0[rr]);
            op[(16 + 4 * g + rr) * 256 + 16 + c] = (ushort)f2bf(oB1[rr]);
            op[(32 + 4 * g + rr) * 256 + c]      = (ushort)f2bf(oC0[rr]);
            op[(32 + 4 * g + rr) * 256 + 16 + c] = (ushort)f2bf(oC1[rr]);
            op[(48 + 4 * g + rr) * 256 + c]      = (ushort)f2bf(oD0[rr]);
            op[(48 + 4 * g + rr) * 256 + 16 + c] = (ushort)f2bf(oD1[rr]);
        }
        if (c == 0) {
            float* lp = lpart + (size_t)(q0 + wv * 64) * 32 + qrt * 8 + h;
#pragma unroll
            for (int rr = 0; rr < 4; ++rr) {
                lp[(size_t)( 0 + 4 * g + rr) * 32] = oAl[rr];
                lp[(size_t)(16 + 4 * g + rr) * 32] = oBl[rr];
                lp[(size_t)(32 + 4 * g + rr) * 32] = oCl[rr];
                lp[(size_t)(48 + 4 * g + rr) * 32] = oDl[rr];
            }
        }
    }
}

// ---------------------------------------------------------------------------
// Fused tail: combine O quarters + attn-proj + LN2 + FF1(gelu) + FF2 +
// proj_out. grid 256, block 1024 (16 waves), 16 tokens per block.
// Weight preloads pinned 8-deep with sched_barrier(0) (see fused_pre note).
// ---------------------------------------------------------------------------
__global__ __launch_bounds__(1024, 4) void fused_tail(
    const ushort* __restrict__ o1, const ushort* __restrict__ o2,
    const ushort* __restrict__ o3, const ushort* __restrict__ o4,
    const float* __restrict__ lpart, const ushort* __restrict__ wb_ap,
    const float* __restrict__ b_ap, const float* __restrict__ ysum,
    const float* __restrict__ ln2_g, const float* __restrict__ ln2_b,
    const ushort* __restrict__ wb_ff1, const float* __restrict__ b_ff1,
    const ushort* __restrict__ wb_ff2, const float* __restrict__ b_ff2,
    const ushort* __restrict__ wb_out, const float* __restrict__ b_out,
    const float* __restrict__ x, float* __restrict__ out)
{
    __shared__ ushort Otile[16 * 264];
    __shared__ ushort Ztile[16 * 264];
    __shared__ ushort Zbig[16 * 1032];
    __shared__ ushort T2tile[16 * 264];
    __shared__ float  red[16][16][2];
    const int t0 = blockIdx.x * 16;
    const int tid = threadIdx.x, wv = tid >> 6, lane = tid & 63;
    const int c = lane & 15, g = lane >> 4;
    const int colp = wv * 16 + c;

    // early: preload attn-proj weight frags (pinned before the combine)
    bf16x8 wap[8];
    {
        const ushort* wp = wb_ap + (size_t)colp * 256 + g * 8;
#pragma unroll
        for (int kc = 0; kc < 8; ++kc) wap[kc] = *(const bf16x8*)(wp + kc * 32);
    }
    SBAR();

    {   // combine O quarters (ushort4 per thread)
        const int r = tid >> 6, c0 = (tid & 63) * 4;
        const int h = (tid & 63) >> 3;   // c0>>5: head of these 4 channels
        const float* lp = lpart + (size_t)(t0 + r) * 32;
        const float inv = 1.0f / (lp[h] + lp[8 + h] + lp[16 + h] + lp[24 + h]);
        const size_t idx = (size_t)(t0 + r) * 256 + c0;
        const ushort4 a = *(const ushort4*)(o1 + idx);
        const ushort4 b = *(const ushort4*)(o2 + idx);
        const ushort4 d = *(const ushort4*)(o3 + idx);
        const ushort4 e = *(const ushort4*)(o4 + idx);
        unsigned w[2];
        w[0] = pk_bf16((bf2f(a.x) + bf2f(b.x) + bf2f(d.x) + bf2f(e.x)) * inv,
                       (bf2f(a.y) + bf2f(b.y) + bf2f(d.y) + bf2f(e.y)) * inv);
        w[1] = pk_bf16((bf2f(a.z) + bf2f(b.z) + bf2f(d.z) + bf2f(e.z)) * inv,
                       (bf2f(a.w) + bf2f(b.w) + bf2f(d.w) + bf2f(e.w)) * inv);
        *(ushort4*)&Otile[r * 264 + c0] = *(ushort4*)w;
    }
    // issue ysum loads early — consumed after the AP-MFMA phase (T14)
    float ysv[4];
#pragma unroll
    for (int rr = 0; rr < 4; ++rr)
        ysv[rr] = ysum[(size_t)(t0 + 4 * g + rr) * 256 + colp];
    __syncthreads();

    // ---- attn-proj: wave w -> cols [16w,16w+16), one frag ----
    f32x4 accp = {};
#pragma unroll
    for (int kc = 0; kc < 8; ++kc) {
        const bf16x8 af = *(const bf16x8*)&Otile[c * 264 + kc * 32 + g * 8];
        accp = MFMA16(af, wap[kc], accp);
    }
    float vsave[4];
    {
        const float bb = b_ap[colp];
        float s1[4], s2[4];
#pragma unroll
        for (int rr = 0; rr < 4; ++rr) {
            const float v = accp[rr] + bb + ysv[rr];
            vsave[rr] = v; s1[rr] = v; s2[rr] = v * v;
        }
#pragma unroll
        for (int rr = 0; rr < 4; ++rr) { s1[rr] = rowsum16(s1[rr]); s2[rr] = rowsum16(s2[rr]); }
        if (c == 0) {
#pragma unroll
            for (int rr = 0; rr < 4; ++rr) {
                red[wv][4 * g + rr][0] = s1[rr];
                red[wv][4 * g + rr][1] = s2[rr];
            }
        }
        __syncthreads();
        if (tid < 32) {
            const int row = tid >> 1, j = tid & 1;
            float s = 0.f;
#pragma unroll
            for (int w = 0; w < 16; ++w) s += red[w][row][j];
            red[0][row][j] = s;
        }
        __syncthreads();
        const float gg = ln2_g[colp], lb = ln2_b[colp];
#pragma unroll
        for (int rr = 0; rr < 4; ++rr) {
            const int row = 4 * g + rr;
            const float mu = red[0][row][0] * (1.0f / 256.0f);
            const float var = red[0][row][1] * (1.0f / 256.0f) - mu * mu;
            const float rs = rsqrtf(var + EPSF);
            const float zv = (vsave[rr] - mu) * rs * gg + lb;
            Ztile[row * 264 + colp] = (ushort)f2bf(zv);
        }
    }
    __syncthreads();

    // ---- FF1 + gelu: wave w -> cols [64w,64w+64); weights preloaded 8-deep
    //      per output-frag, load group pinned ----
    {
        const ushort* wf1 = wb_ff1 + (size_t)(wv * 64 + c) * 256 + g * 8;
        f32x4 accf[4] = {};
#pragma unroll
        for (int nf = 0; nf < 4; ++nf) {
            bf16x8 wf[8];
#pragma unroll
            for (int kc = 0; kc < 8; ++kc)
                wf[kc] = *(const bf16x8*)(wf1 + (size_t)nf * 4096 + kc * 32);
            SBAR();
#pragma unroll
            for (int kc = 0; kc < 8; ++kc) {
                const bf16x8 af = *(const bf16x8*)&Ztile[c * 264 + kc * 32 + g * 8];
                accf[nf] = MFMA16(af, wf[kc], accf[nf]);
            }
        }
#pragma unroll
        for (int nf = 0; nf < 4; ++nf) {
            const int col = wv * 64 + nf * 16 + c;
            const float bb = b_ff1[col];
#pragma unroll
            for (int rr = 0; rr < 4; ++rr) {
                const float v = gelu_f(accf[nf][rr] + bb);
                Zbig[(4 * g + rr) * 1032 + col] = (ushort)f2bf(v);
            }
        }
    }
    __syncthreads();

    // ---- FF2: K=1024, weights preloaded 8-deep per chunk (pinned),
    //      2 acc chains ----
    {
        const ushort* wf2 = wb_ff2 + (size_t)colp * 1024 + g * 8;
        f32x4 acc0 = {}, acc1 = {};
#pragma unroll
        for (int ch = 0; ch < 4; ++ch) {
            bf16x8 wf[8];
#pragma unroll
            for (int kk = 0; kk < 8; ++kk)
                wf[kk] = *(const bf16x8*)(wf2 + (ch * 8 + kk) * 32);
            SBAR();
#pragma unroll
            for (int kk = 0; kk < 8; ++kk) {
                const int kc = ch * 8 + kk;
                const bf16x8 af = *(const bf16x8*)&Zbig[c * 1032 + kc * 32 + g * 8];
                if (kk & 1) acc1 = MFMA16(af, wf[kk], acc1);
                else        acc0 = MFMA16(af, wf[kk], acc0);
            }
        }
        const float bb = b_ff2[colp];
#pragma unroll
        for (int rr = 0; rr < 4; ++rr) {
            const float v = acc0[rr] + acc1[rr] + bb + vsave[rr];
            T2tile[(4 * g + rr) * 264 + colp] = (ushort)f2bf(v);
        }
    }
    // preload proj_out weights + x residual before the last barrier (T14)
    bf16x8 wout[8];
    {
        const ushort* wo = wb_out + (size_t)colp * 256 + g * 8;
#pragma unroll
        for (int kc = 0; kc < 8; ++kc) wout[kc] = *(const bf16x8*)(wo + kc * 32);
    }
    float xres[4];
#pragma unroll
    for (int rr = 0; rr < 4; ++rr)
        xres[rr] = x[(size_t)(wv * 16 + 4 * g + rr) * T_TOK + t0 + c];
    SBAR();
    __syncthreads();

    // ---- proj_out: wave w -> out rows [16w,16w+16) ----
    f32x4 acco = {};
#pragma unroll
    for (int kc = 0; kc < 8; ++kc) {
        const bf16x8 bfr = *(const bf16x8*)&T2tile[c * 264 + kc * 32 + g * 8]; // B: token=c
        acco = MFMA16(wout[kc], bfr, acco);
    }
#pragma unroll
    for (int rr = 0; rr < 4; ++rr) {
        const int och = wv * 16 + 4 * g + rr;
        const size_t idx = (size_t)och * T_TOK + t0 + c;
        out[idx] = acco[rr] + b_out[och] + xres[rr];
    }
}

// ---------------------------------------------------------------------------
extern "C" void kernel_launch(void* const* d_in, const int* in_sizes, int n_in,
                              void* d_out, int out_size, void* d_ws, size_t ws_size,
                              hipStream_t stream)
{
    const float* x     = (const float*)d_in[0];
    const float* bn_g  = (const float*)d_in[1];
    const float* bn_b  = (const float*)d_in[2];
    const float* bn_m  = (const float*)d_in[3];
    const float* bn_v  = (const float*)d_in[4];
    const float* w_in  = (const float*)d_in[5];
    const float* b_in  = (const float*)d_in[6];
    const float* ln1_g = (const float*)d_in[7];
    const float* ln1_b = (const float*)d_in[8];
    const float* w_qkv = (const float*)d_in[9];
    const float* b_qkv = (const float*)d_in[10];
    const float* w_ap  = (const float*)d_in[11];
    const float* b_ap  = (const float*)d_in[12];
    const float* ln2_g = (const float*)d_in[13];
    const float* ln2_b = (const float*)d_in[14];
    const float* w_ff1 = (const float*)d_in[15];
    const float* b_ff1 = (const float*)d_in[16];
    const float* w_ff2 = (const float*)d_in[17];
    const float* b_ff2 = (const float*)d_in[18];
    const float* w_out = (const float*)d_in[19];
    const float* b_out = (const float*)d_in[20];
    float* out = (float*)d_out;
    float* ws  = (float*)d_ws;

    const size_t MF = 1u << 20;   // 1M f32 = 4 MB
    float*  ysum   = ws + MF;                           // [1M,2M)
    ushort* qkv_bf = (ushort*)(ws + 3 * MF);            // [3M,4.5M)
    ushort* o1p    = (ushort*)(ws + 6 * MF + MF / 2);   // [6.5M,7M)
    ushort* o2p    = (ushort*)(ws + 7 * MF);            // [7M,7.5M)
    ushort* o3p    = (ushort*)(ws + 7 * MF + MF / 2);   // [7.5M,8M)
    ushort* o4p    = (ushort*)(ws + 8 * MF);            // [8M,8.5M)
    float*  lpart  = ws + 8 * MF + MF / 2;              // [8.5M,+128K f32 = 512KB)
    ushort* wbuf   = (ushort*)(ws + 8 * MF + MF / 2 + 131072);  // weight arena
    const ushort* wb_in  = wbuf;
    const ushort* wb_qkv = wbuf + 65536;
    const ushort* wb_ap  = wbuf + 262144;
    const ushort* wb_ff1 = wbuf + 327680;
    const ushort* wb_ff2 = wbuf + 589824;
    const ushort* wb_out = wbuf + 851968;
    float* bqs = (float*)(wbuf + 917504);

    prep_kernel<<<896, 256, 0, stream>>>(w_in, w_qkv, w_ap, w_ff1, w_ff2, w_out,
                                         b_qkv, wbuf, bqs);
    fused_pre<<<256, 1024, 0, stream>>>(x, bn_g, bn_b, bn_m, bn_v,
                                        wb_in, b_in, ln1_g, ln1_b,
                                        wb_qkv, bqs, ysum, qkv_bf);
    attn_mfma<<<dim3(16, 8, 4), 256, 0, stream>>>(qkv_bf, o1p, o2p, o3p, o4p, lpart);
    fused_tail<<<256, 1024, 0, stream>>>(o1p, o2p, o3p, o4p, lpart, wb_ap, b_ap,
                                         ysum, ln2_g, ln2_b, wb_ff1, b_ff1,
                                         wb_ff2, b_ff2, wb_out, b_out, x, out);
}